// Round 14
// baseline (551.351 us; speedup 1.0000x reference)
//
#include <hip/hip_runtime.h>
#include <hip/hip_bf16.h>
#include <math.h>

// SeaLiceGLKAN — fp32 in/out. Node-local fusion, no grid sync:
//   k_mega: MFMA dense chain + cell + NEXT-step hop0 matvec tail
//   k_hop_agg: softmax edge aggregate + NEXT hop matvec tail (VALU, L1 weights)
// hw/ssrc/sdst double-buffered (A: hop0/hop2, B: hop1) to break WAR across blocks.

constexpr int cB = 2, cT = 4, cN = 10000, cF = 16, cH = 64, cE = 160000, cK = 3;
constexpr int cBN = cB * cN;    // 20000
constexpr int cBNH = cBN * cH;  // 1,280,000
constexpr int NBLK = (cBN + 63) / 64;  // 313 nodegroups of 64

typedef const float* fp;
typedef short short8 __attribute__((ext_vector_type(8)));
typedef float f32x4 __attribute__((ext_vector_type(4)));
typedef unsigned short u16;

__device__ __forceinline__ float wsum(float v) {
#pragma unroll
  for (int o = 1; o < 64; o <<= 1) v += __shfl_xor(v, o, 64);
  return v;
}
__device__ __forceinline__ u16 f2b(float f) {  // fp32 -> bf16 bits (RNE)
  unsigned u = __float_as_uint(f);
  u += 0x7FFFu + ((u >> 16) & 1u);
  return (u16)(u >> 16);
}
__device__ __forceinline__ float b2f(u16 b) { return __uint_as_float(((unsigned)b) << 16); }

// ---------------- CSR build ----------------
__global__ void k_count(const int* dst, int* counts) {
  int e = blockIdx.x * 256 + threadIdx.x;
  if (e < cE) atomicAdd(&counts[dst[e]], 1);
}

__global__ void k_scan(const int* counts, int* row_ptr, int* cursor) {
  __shared__ int part[1024];
  int t = threadIdx.x;
  const int CH = (cN + 1023) / 1024;  // 10
  int s = 0;
  for (int i = 0; i < CH; i++) {
    int idx = t * CH + i;
    if (idx < cN) s += counts[idx];
  }
  part[t] = s;
  __syncthreads();
  for (int off = 1; off < 1024; off <<= 1) {
    int v = (t >= off) ? part[t - off] : 0;
    __syncthreads();
    part[t] += v;
    __syncthreads();
  }
  int excl = (t == 0) ? 0 : part[t - 1];
  for (int i = 0; i < CH; i++) {
    int idx = t * CH + i;
    if (idx < cN) {
      row_ptr[idx] = excl;
      cursor[idx] = excl;
      excl += counts[idx];
    }
  }
  if (t == 1023) row_ptr[cN] = part[1023];
}

__global__ void k_scatter(const int* src, const int* dst, fp ea, fp w1, fp b1, fp w2, fp b2,
                          int* cursor, int* esrc, float* gcsr) {
  int e = blockIdx.x * 256 + threadIdx.x;
  if (e >= cE) return;
  float a0 = ea[e * 4 + 0], a1 = ea[e * 4 + 1], a2 = ea[e * 4 + 2], a3 = ea[e * 4 + 3];
  float acc = b2[0];
#pragma unroll
  for (int j = 0; j < 16; j++) {
    float tv = b1[j] + a0 * w1[j] + a1 * w1[16 + j] + a2 * w1[32 + j] + a3 * w1[48 + j];
    acc += tanhf(tv) * w2[j];
  }
  float g = 1.f / (1.f + expf(-acc));
  int p = atomicAdd(&cursor[dst[e]], 1);
  esrc[p] = src[e];
  gcsr[p] = g;
}

// ---------------- setup: counts zero + h init + weight prepack ----------------
constexpr int cWTOT = 128 * 160 + 64 * 128 + 64 * 64 + 3 * 64 * 64;  // 45056
__global__ void k_setup(int* counts, float* h, u16* h_bf, fp h0, fp W_tau, fp W_g, fp W_enc,
                        fp W_lt, fp W_hop, u16* Wtg, u16* Wenc, u16* Wlt, u16* Whop) {
  int i = blockIdx.x * 256 + threadIdx.x;
  if (i < cN) counts[i] = 0;
  if (i < cBNH) {
    float v = h0[i & 63];
    h[i] = v;
    h_bf[i] = f2b(v);
  }
  if (i < 128 * 160) {
    int col = i / 160, k = i - col * 160;
    float v = 0.f;
    if (k < 133) v = (col < 64) ? W_tau[k * 64 + col] : W_g[k * 64 + (col - 64)];
    Wtg[i] = f2b(v);
  } else if (i < 128 * 160 + 64 * 128) {
    int i2 = i - 128 * 160;
    int col = i2 / 128, k = i2 - col * 128;
    Wenc[i2] = f2b(W_enc[k * 64 + col]);
  } else if (i < 128 * 160 + 64 * 128 + 64 * 64) {
    int i3 = i - 128 * 160 - 64 * 128;
    int col = i3 / 64, k = i3 - col * 64;
    Wlt[i3] = f2b(W_lt[k * 64 + col]);
  } else if (i < cWTOT) {
    int i4 = i - 128 * 160 - 64 * 128 - 64 * 64;
    int hop = i4 / 4096, rem = i4 - hop * 4096;
    int col = rem / 64, k = rem - col * 64;
    Whop[i4] = f2b(W_hop[hop * 4096 + k * 64 + col]);
  }
}

// ---------------- hop matvec (standalone, used once for t=0 hop0): MFMA bf16 ----------
__global__ __launch_bounds__(256) void k_hop_mat_m(const u16* vin_bf, const u16* Wh, fp avs,
                                                   fp avd, u16* hw_bf, float* ssrc,
                                                   float* sdst) {
  __shared__ u16 tin[64 * 72];
  __shared__ u16 thw[64 * 72];
  __shared__ float red1[4][64], red2[4][64];
  int tid = threadIdx.x, w = tid >> 6, lane = tid & 63;
  int quad = lane >> 4, l15 = lane & 15;
  int base = blockIdx.x * 64;
  {
    int tn = tid >> 2, cs = (tid & 3) * 16;
    int gn = base + tn;
    if (gn >= cBN) gn = cBN - 1;
    const short8* src = (const short8*)(vin_bf + (size_t)gn * 64 + cs);
    *(short8*)(tin + tn * 72 + cs) = src[0];
    *(short8*)(tin + tn * 72 + cs + 8) = src[1];
  }
  __syncthreads();
  f32x4 acc[4];
#pragma unroll
  for (int mt = 0; mt < 4; mt++) acc[mt] = (f32x4){0.f, 0.f, 0.f, 0.f};
#pragma unroll
  for (int ks = 0; ks < 2; ks++) {
    short8 bfr = *(const short8*)(Wh + (16 * w + l15) * 64 + ks * 32 + quad * 8);
#pragma unroll
    for (int mt = 0; mt < 4; mt++) {
      short8 afr = *(const short8*)(tin + (mt * 16 + l15) * 72 + ks * 32 + quad * 8);
      acc[mt] = __builtin_amdgcn_mfma_f32_16x16x32_bf16(afr, bfr, acc[mt], 0, 0, 0);
    }
  }
  int col = 16 * w + l15;
#pragma unroll
  for (int mt = 0; mt < 4; mt++) {
#pragma unroll
    for (int r = 0; r < 4; r++) {
      thw[(mt * 16 + quad * 4 + r) * 72 + col] = f2b(acc[mt][r]);
    }
  }
  __syncthreads();
  {
    float r1 = 0.f, r2 = 0.f;
#pragma unroll
    for (int c = 0; c < 16; c++) {
      float v = b2f(thw[lane * 72 + 16 * w + c]);
      r1 += v * avs[16 * w + c];
      r2 += v * avd[16 * w + c];
    }
    red1[w][lane] = r1;
    red2[w][lane] = r2;
  }
  __syncthreads();
  if (w == 0 && base + lane < cBN) {
    ssrc[base + lane] = red1[0][lane] + red1[1][lane] + red1[2][lane] + red1[3][lane];
    sdst[base + lane] = red2[0][lane] + red2[1][lane] + red2[2][lane] + red2[3][lane];
  }
  {
    int tn = tid >> 2, cs = (tid & 3) * 16;
    int gn = base + tn;
    if (gn < cBN) {
      short8* dst = (short8*)(hw_bf + (size_t)gn * 64 + cs);
      dst[0] = *(const short8*)(thw + tn * 72 + cs);
      dst[1] = *(const short8*)(thw + tn * 72 + cs + 8);
    }
  }
}

// ---------------- hop aggregate (2 edges/iter) + fused NEXT-hop matvec tail ----------
__global__ __launch_bounds__(256) void k_hop_agg(const u16* hw_bf, const float* ssrc,
                                                 const float* sdst, const int* row_ptr,
                                                 const int* esrc, const float* gcsr,
                                                 const u16* h_bf, float* khsum, u16* agg_bf,
                                                 int hop, fp Whop_next, fp avs_n, fp avd_n,
                                                 u16* hw_out, float* ssrc_out, float* sdst_out,
                                                 int do_tail) {
  __shared__ float scur[4][64];
  int w = threadIdx.x >> 6, lane = threadIdx.x & 63;
  int half = lane >> 5, hl = lane & 31;
  int u = blockIdx.x * 4 + w;
  int b = u / cN, n = u - b * cN;
  int r0 = row_ptr[n], r1e = row_ptr[n + 1];
  const float* sb = ssrc + (size_t)b * cN;
  float sd = sdst[u];
  float den = 0.f, num0 = 0.f, num1 = 0.f, la0 = 0.f, la1 = 0.f;
  const u16* hwb = hw_bf + (size_t)b * cN * 64;
  const u16* hb = h_bf + (size_t)b * cN * 64;
  for (int e0 = r0; e0 < r1e; e0 += 64) {
    int e = e0 + lane;
    bool vld = e < r1e;
    int s = vld ? esrc[e] : 0;
    float g = (hop == 0 && vld) ? gcsr[e] : 0.f;
    float a = 0.f;
    if (vld) {
      float ev = sb[s] + sd;
      ev = ev > 0.f ? ev : 0.2f * ev;
      a = __expf(ev);  // |ev| small; softmax shift-invariant
    }
    den += a;
    int cnt = min(64, r1e - e0);
    for (int j = 0; j < cnt; j += 2) {
      int sA = __builtin_amdgcn_readlane(s, j);
      int sB = __builtin_amdgcn_readlane(s, j + 1);  // a=0 pads odd tails
      float aA = __uint_as_float(__builtin_amdgcn_readlane(__float_as_uint(a), j));
      float aB = __uint_as_float(__builtin_amdgcn_readlane(__float_as_uint(a), j + 1));
      int sj = half ? sB : sA;
      float aj = half ? aB : aA;
      unsigned d = *(const unsigned*)(hwb + (size_t)sj * 64 + hl * 2);
      num0 += aj * __uint_as_float(d << 16);
      num1 += aj * __uint_as_float(d & 0xffff0000u);
      if (hop == 0) {
        float gA = __uint_as_float(__builtin_amdgcn_readlane(__float_as_uint(g), j));
        float gB = __uint_as_float(__builtin_amdgcn_readlane(__float_as_uint(g), j + 1));
        float gj = half ? gB : gA;
        unsigned dh = *(const unsigned*)(hb + (size_t)sj * 64 + hl * 2);
        la0 += gj * __uint_as_float(dh << 16);
        la1 += gj * __uint_as_float(dh & 0xffff0000u);
      }
    }
  }
  den = wsum(den);
  num0 += __shfl_xor(num0, 32);
  num1 += __shfl_xor(num1, 32);
  if (hop == 0) {
    la0 += __shfl_xor(la0, 32);
    la1 += __shfl_xor(la1, 32);
  }
  float inv = 1.f / (den + 1e-16f);
  if (half == 0) {
    float c0v = num0 * inv, c1v = num1 * inv;
    size_t ni = (size_t)u * 64 + hl * 2;
    if (do_tail) {
      scur[w][hl * 2] = c0v;
      scur[w][hl * 2 + 1] = c1v;
    }
    float2* kp2 = (float2*)(khsum + ni);
    if (hop == 0) {
      float2 kv;
      kv.x = c0v;
      kv.y = c1v;
      *kp2 = kv;
      *(unsigned*)(agg_bf + ni) = ((unsigned)f2b(la1) << 16) | (unsigned)f2b(la0);
    } else {
      float2 kv = *kp2;
      kv.x += c0v;
      kv.y += c1v;
      *kp2 = kv;
    }
  }
  // ---- fused tail: next-hop matvec for this node (wave-local LDS, L1 weights) ----
  if (do_tail) {
    float hwv = 0.f;
#pragma unroll 8
    for (int kk = 0; kk < 64; kk++) hwv += scur[w][kk] * Whop_next[kk * 64 + lane];
    float r1 = wsum(hwv * avs_n[lane]);
    float r2 = wsum(hwv * avd_n[lane]);
    if (lane == 0) {
      ssrc_out[u] = r1;
      sdst_out[u] = r2;
    }
    hw_out[(size_t)u * 64 + lane] = f2b(hwv);
  }
}

// ---------------- MFMA mega-kernel: p-GEMM + tau/g GEMM + u GEMM + cell + next hop0 mat --
__global__ __launch_bounds__(256) void k_mega(fp x, int t, float* h_nm, u16* h_bf,
                                              const float* khsum, const u16* agg_bf,
                                              const int* row_ptr, const u16* Wtg,
                                              const u16* Wenc, const u16* Wlt, const u16* Whop0,
                                              fp avs0, fp avd0, u16* hw_bf, float* ssrc,
                                              float* sdst, fp b_tau, fp b_g, fp b_enc, fp gamma,
                                              fp beta, fp c_enc, fp cdec, fp W_dec, fp b_dec,
                                              float* out) {
  __shared__ __align__(16) char lds[59904];
  u16* tz = (u16*)lds;                  // [64][168] bf16
  u16* tphi = (u16*)(lds + 30720);      // [64][136] bf16
  float* tgu = (float*)lds;             // [64][197] fp32 overlay (after GEMMs)
  u16* tzh = (u16*)lds;                 // [64][72] bf16 (tail overlay)
  u16* thw2 = (u16*)(lds + 10240);      // [64][72] bf16 (tail overlay)
  float* sx = (float*)(lds + 50432);
  float* redm = (float*)(lds + 54784);  // [4][64]
  float* redv = redm + 256;             // [4][64]
  float* redp = redv + 256;             // [4][3][64]
  int tid = threadIdx.x;
  int w = tid >> 6, lane = tid & 63;
  int quad = lane >> 4, l15 = lane & 15;
  int base = blockIdx.x * 64;
  {
    int tn = tid >> 2, f4 = (tid & 3) * 4;
    int gn = base + tn;
    if (gn >= cBN) gn = cBN - 1;
    int gb = gn / cN, gnn = gn - gb * cN;
    float4 xv = *(const float4*)(x + (((size_t)gb * cT + t) * cN + gnn) * cF + f4);
    sx[tn * 17 + f4 + 0] = xv.x;
    sx[tn * 17 + f4 + 1] = xv.y;
    sx[tn * 17 + f4 + 2] = xv.z;
    sx[tn * 17 + f4 + 3] = xv.w;
    int f0 = (tid & 3) * 16;
    const short8* hs = (const short8*)(h_bf + (size_t)gn * 64 + f0);
    *(short8*)(tz + tn * 168 + f0) = hs[0];
    *(short8*)(tz + tn * 168 + f0 + 8) = hs[1];
  }
  for (int i = tid; i < 64 * 27; i += 256) {
    int nn2 = i / 27;
    tz[nn2 * 168 + 133 + (i - nn2 * 27)] = 0;
  }
  __syncthreads();
  for (int i = tid; i < 320; i += 256) {
    int j = i >> 6, n2 = i & 63;
    tz[n2 * 168 + 64 + j] = f2b(sx[n2 * 17 + 8 + j]);
  }
  {
    float ec0 = c_enc[0], ec7 = c_enc[7];
    float inv_e = 7.f / (ec7 - ec0);
    for (int i = tid; i < 64 * 128; i += 256) {
      int n2 = i >> 7, j = i & 127;
      int f = j >> 3, cb = j & 7;
      float d = (sx[n2 * 17 + f] - c_enc[cb]) * inv_e;
      tphi[n2 * 136 + j] = f2b(__expf(-d * d));
    }
  }
  __syncthreads();
  // G2: u = phi @ Wenc
  f32x4 accU[4];
#pragma unroll
  for (int mt = 0; mt < 4; mt++) accU[mt] = (f32x4){0.f, 0.f, 0.f, 0.f};
#pragma unroll
  for (int ks = 0; ks < 4; ks++) {
    short8 bfr = *(const short8*)(Wenc + (16 * w + l15) * 128 + ks * 32 + quad * 8);
#pragma unroll
    for (int mt = 0; mt < 4; mt++) {
      short8 afr = *(const short8*)(tphi + (mt * 16 + l15) * 136 + ks * 32 + quad * 8);
      accU[mt] = __builtin_amdgcn_mfma_f32_16x16x32_bf16(afr, bfr, accU[mt], 0, 0, 0);
    }
  }
  // G0: plt = agg @ Wlt -> p rows into tz
  {
    f32x4 accP[4];
#pragma unroll
    for (int mt = 0; mt < 4; mt++) accP[mt] = (f32x4){0.f, 0.f, 0.f, 0.f};
#pragma unroll
    for (int ks = 0; ks < 2; ks++) {
      short8 bfr = *(const short8*)(Wlt + (16 * w + l15) * 64 + ks * 32 + quad * 8);
#pragma unroll
      for (int mt = 0; mt < 4; mt++) {
        int gn = base + mt * 16 + l15;
        if (gn >= cBN) gn = cBN - 1;
        short8 afr = *(const short8*)(agg_bf + (size_t)gn * 64 + ks * 32 + quad * 8);
        accP[mt] = __builtin_amdgcn_mfma_f32_16x16x32_bf16(afr, bfr, accP[mt], 0, 0, 0);
      }
    }
    int colP = 16 * w + l15;
#pragma unroll
    for (int mt = 0; mt < 4; mt++) {
#pragma unroll
      for (int r = 0; r < 4; r++) {
        int nl = mt * 16 + quad * 4 + r;
        int gn = base + nl;
        int gnc = gn < cBN ? gn : cBN - 1;
        int bB = gnc / cN, nn = gnc - bB * cN;
        float deg = (float)(row_ptr[nn + 1] - row_ptr[nn]);
        float pv = khsum[(size_t)gnc * 64 + colP] * (1.f / 3.f) + accP[mt][r] / (deg + 1.f);
        tz[nl * 168 + 69 + colP] = f2b(pv);
      }
    }
  }
  __syncthreads();
  // G1: [tau|g] = z @ Wtg (K=160)
  f32x4 accT[8];
#pragma unroll
  for (int i = 0; i < 8; i++) accT[i] = (f32x4){0.f, 0.f, 0.f, 0.f};
#pragma unroll
  for (int ks = 0; ks < 5; ks++) {
    short8 b0 = *(const short8*)(Wtg + (32 * w + l15) * 160 + ks * 32 + quad * 8);
    short8 b1 = *(const short8*)(Wtg + (32 * w + 16 + l15) * 160 + ks * 32 + quad * 8);
#pragma unroll
    for (int mt = 0; mt < 4; mt++) {
      short8 afr = *(const short8*)(tz + (mt * 16 + l15) * 168 + ks * 32 + quad * 8);
      accT[mt * 2 + 0] =
          __builtin_amdgcn_mfma_f32_16x16x32_bf16(afr, b0, accT[mt * 2 + 0], 0, 0, 0);
      accT[mt * 2 + 1] =
          __builtin_amdgcn_mfma_f32_16x16x32_bf16(afr, b1, accT[mt * 2 + 1], 0, 0, 0);
    }
  }
  __syncthreads();  // tz dead; tgu overlay
#pragma unroll
  for (int mt = 0; mt < 4; mt++) {
#pragma unroll
    for (int ntl = 0; ntl < 2; ntl++) {
#pragma unroll
      for (int r = 0; r < 4; r++) {
        int nl = mt * 16 + quad * 4 + r;
        tgu[nl * 197 + 32 * w + ntl * 16 + l15] = accT[mt * 2 + ntl][r];
      }
    }
#pragma unroll
    for (int r = 0; r < 4; r++) {
      int nl = mt * 16 + quad * 4 + r;
      tgu[nl * 197 + 128 + 16 * w + l15] = accU[mt][r];
    }
  }
  __syncthreads();
  // epilogue: thread = node lane, col chunk c0
  int c0 = __builtin_amdgcn_readfirstlane(w * 16);
  int node = base + lane;
  int ngc = node < cBN ? node : cBN - 1;
  int bb = ngc / cN, nn = ngc - bb * cN;
  float hv[16];
  {
    const float4* hp = (const float4*)(h_nm + (size_t)ngc * 64 + c0);
#pragma unroll
    for (int q = 0; q < 4; q++) {
      float4 v = hp[q];
      hv[q * 4 + 0] = v.x; hv[q * 4 + 1] = v.y; hv[q * 4 + 2] = v.z; hv[q * 4 + 3] = v.w;
    }
  }
  float acc[16];
  float pm = 0.f;
#pragma unroll
  for (int c = 0; c < 16; c++) {
    float at = tgu[lane * 197 + c0 + c] + b_tau[c0 + c];
    float ag = tgu[lane * 197 + 64 + c0 + c] + b_g[c0 + c];
    float tau = 1.f + 9.f / (1.f + __expf(-at));
    float g = tanhf(ag);
    float v = hv[c] + 0.25f * (g - hv[c]) / tau;
    acc[c] = v;
    pm += v;
  }
  redm[w * 64 + lane] = pm;
  __syncthreads();
  float mu = (redm[lane] + redm[64 + lane] + redm[128 + lane] + redm[192 + lane]) * (1.f / 64.f);
  float pv = 0.f;
#pragma unroll
  for (int c = 0; c < 16; c++) {
    float d = acc[c] - mu;
    pv += d * d;
  }
  redv[w * 64 + lane] = pv;
  __syncthreads();
  float var = (redv[lane] + redv[64 + lane] + redv[128 + lane] + redv[192 + lane]) * (1.f / 64.f);
  float rstd = rsqrtf(var + 1e-5f);
#pragma unroll
  for (int c = 0; c < 16; c++) {
    acc[c] = (acc[c] - mu) * rstd * gamma[c0 + c] + beta[c0 + c] +
             tgu[lane * 197 + 128 + c0 + c] + b_enc[c0 + c];
  }
  if (node < cBN) {
    float4* hp = (float4*)(h_nm + (size_t)ngc * 64 + c0);
#pragma unroll
    for (int q = 0; q < 4; q++) {
      float4 v;
      v.x = acc[q * 4 + 0]; v.y = acc[q * 4 + 1]; v.z = acc[q * 4 + 2]; v.w = acc[q * 4 + 3];
      hp[q] = v;
    }
    unsigned* bp = (unsigned*)(h_bf + (size_t)ngc * 64 + c0);
#pragma unroll
    for (int q = 0; q < 8; q++) {
      unsigned lo = f2b(acc[q * 2 + 0]);
      unsigned hi = f2b(acc[q * 2 + 1]);
      bp[q] = (hi << 16) | lo;
    }
  }
  // decoder fastkan + softplus
  float dc0 = cdec[0], dc7 = cdec[7];
  float inv_d = 7.f / (dc7 - dc0);
  float p0 = 0.f, p1 = 0.f, p2 = 0.f;
#pragma unroll
  for (int c = 0; c < 16; c++) {
#pragma unroll
    for (int j = 0; j < 8; j++) {
      float dd = (acc[c] - cdec[j]) * inv_d;
      float ph = __expf(-dd * dd);
      int bx = ((c0 + c) * 8 + j) * 3;
      p0 += ph * W_dec[bx];
      p1 += ph * W_dec[bx + 1];
      p2 += ph * W_dec[bx + 2];
    }
  }
  redp[(w * 3 + 0) * 64 + lane] = p0;
  redp[(w * 3 + 1) * 64 + lane] = p1;
  redp[(w * 3 + 2) * 64 + lane] = p2;
  __syncthreads();  // also: all tgu reads complete -> tail overlay safe
  if (w == 0 && node < cBN) {
    float v0 = redp[0 * 64 + lane] + redp[3 * 64 + lane] + redp[6 * 64 + lane] +
               redp[9 * 64 + lane] + b_dec[0];
    float v1 = redp[1 * 64 + lane] + redp[4 * 64 + lane] + redp[7 * 64 + lane] +
               redp[10 * 64 + lane] + b_dec[1];
    float v2 = redp[2 * 64 + lane] + redp[5 * 64 + lane] + redp[8 * 64 + lane] +
               redp[11 * 64 + lane] + b_dec[2];
    size_t ob = (((size_t)bb * cT + t) * cN + nn) * 3;
    out[ob] = fmaxf(v0, 0.f) + log1pf(expf(-fabsf(v0)));
    out[ob + 1] = fmaxf(v1, 0.f) + log1pf(expf(-fabsf(v1)));
    out[ob + 2] = fmaxf(v2, 0.f) + log1pf(expf(-fabsf(v2)));
  }
  // ---- fused tail: next-step hop0 matvec (node-local: uses just-computed h) ----
#pragma unroll
  for (int c = 0; c < 16; c++) tzh[lane * 72 + c0 + c] = f2b(acc[c]);
  __syncthreads();
  f32x4 hacc[4];
#pragma unroll
  for (int mt = 0; mt < 4; mt++) hacc[mt] = (f32x4){0.f, 0.f, 0.f, 0.f};
#pragma unroll
  for (int ks = 0; ks < 2; ks++) {
    short8 bfr = *(const short8*)(Whop0 + (16 * w + l15) * 64 + ks * 32 + quad * 8);
#pragma unroll
    for (int mt = 0; mt < 4; mt++) {
      short8 afr = *(const short8*)(tzh + (mt * 16 + l15) * 72 + ks * 32 + quad * 8);
      hacc[mt] = __builtin_amdgcn_mfma_f32_16x16x32_bf16(afr, bfr, hacc[mt], 0, 0, 0);
    }
  }
  int colh = 16 * w + l15;
#pragma unroll
  for (int mt = 0; mt < 4; mt++) {
#pragma unroll
    for (int r = 0; r < 4; r++) {
      thw2[(mt * 16 + quad * 4 + r) * 72 + colh] = f2b(hacc[mt][r]);
    }
  }
  __syncthreads();
  {
    float r1 = 0.f, r2 = 0.f;
#pragma unroll
    for (int c = 0; c < 16; c++) {
      float v = b2f(thw2[lane * 72 + 16 * w + c]);
      r1 += v * avs0[16 * w + c];
      r2 += v * avd0[16 * w + c];
    }
    redm[w * 64 + lane] = r1;
    redv[w * 64 + lane] = r2;
  }
  __syncthreads();
  if (w == 0 && node < cBN) {
    ssrc[node] = redm[lane] + redm[64 + lane] + redm[128 + lane] + redm[192 + lane];
    sdst[node] = redv[lane] + redv[64 + lane] + redv[128 + lane] + redv[192 + lane];
  }
  {
    int tn = tid >> 2, cs = (tid & 3) * 16;
    int gn = base + tn;
    if (gn < cBN) {
      short8* dst = (short8*)(hw_bf + (size_t)gn * 64 + cs);
      dst[0] = *(const short8*)(thw2 + tn * 72 + cs);
      dst[1] = *(const short8*)(thw2 + tn * 72 + cs + 8);
    }
  }
}

extern "C" void kernel_launch(void* const* d_in, const int* in_sizes, int n_in, void* d_out,
                              int out_size, void* d_ws, size_t ws_size, hipStream_t stream) {
  fp x = (fp)d_in[0];
  fp edge_attr = (fp)d_in[1];
  fp c_enc = (fp)d_in[2];
  fp W_enc = (fp)d_in[3];
  fp b_enc = (fp)d_in[4];
  fp W_hop = (fp)d_in[5];
  fp a_src = (fp)d_in[6];
  fp a_dst = (fp)d_in[7];
  fp w_lt1 = (fp)d_in[8];
  fp b_lt1 = (fp)d_in[9];
  fp w_lt2 = (fp)d_in[10];
  fp b_lt2 = (fp)d_in[11];
  fp W_lt = (fp)d_in[12];
  fp W_tau = (fp)d_in[13];
  fp b_tau = (fp)d_in[14];
  fp W_g = (fp)d_in[15];
  fp b_g = (fp)d_in[16];
  fp gamma = (fp)d_in[17];
  fp beta = (fp)d_in[18];
  fp c_dec = (fp)d_in[19];
  fp W_dec = (fp)d_in[20];
  fp b_dec = (fp)d_in[21];
  fp h0 = (fp)d_in[22];
  const int* eidx = (const int*)d_in[23];
  const int* esrc_in = eidx;
  const int* edst_in = eidx + cE;

  float* fws = (float*)d_ws;
  float* h_nm = fws;   fws += cBNH;
  float* khsum = fws;  fws += cBNH;
  float* ssrcA = fws;  fws += cBN;
  float* sdstA = fws;  fws += cBN;
  float* ssrcB = fws;  fws += cBN;
  float* sdstB = fws;  fws += cBN;
  float* gcsr = fws;   fws += cE;
  u16* h_bf = (u16*)fws;   fws += cBNH / 2;
  u16* hwA = (u16*)fws;    fws += cBNH / 2;
  u16* hwB = (u16*)fws;    fws += cBNH / 2;
  u16* agg_bf = (u16*)fws; fws += cBNH / 2;
  u16* Wtg = (u16*)fws;   fws += (128 * 160) / 2;
  u16* Wenc = (u16*)fws;  fws += (64 * 128) / 2;
  u16* Wlt = (u16*)fws;   fws += (64 * 64) / 2;
  u16* Whop = (u16*)fws;  fws += (3 * 64 * 64) / 2;
  int* iws = (int*)fws;
  int* esrc = iws;    iws += cE;
  int* row_ptr = iws; iws += cN + 1;
  int* cursor = iws;  iws += cN;
  int* counts = iws;  iws += cN;

  k_setup<<<(cBNH + 255) / 256, 256, 0, stream>>>(counts, h_nm, h_bf, h0, W_tau, W_g, W_enc,
                                                  W_lt, W_hop, Wtg, Wenc, Wlt, Whop);
  k_count<<<(cE + 255) / 256, 256, 0, stream>>>(edst_in, counts);
  k_scan<<<1, 1024, 0, stream>>>(counts, row_ptr, cursor);
  k_scatter<<<(cE + 255) / 256, 256, 0, stream>>>(esrc_in, edst_in, edge_attr, w_lt1, b_lt1,
                                                  w_lt2, b_lt2, cursor, esrc, gcsr);
  // initial hop0 matvec for t=0 (later steps get it fused into k_mega's tail)
  k_hop_mat_m<<<NBLK, 256, 0, stream>>>(h_bf, Whop, a_src, a_dst, hwA, ssrcA, sdstA);

  for (int t = 0; t < cT; t++) {
    // hop0: read A, tail -> B (hop1)
    k_hop_agg<<<cBN / 4, 256, 0, stream>>>(hwA, ssrcA, sdstA, row_ptr, esrc, gcsr, h_bf, khsum,
                                           agg_bf, 0, W_hop + 4096, a_src + cH, a_dst + cH, hwB,
                                           ssrcB, sdstB, 1);
    // hop1: read B, tail -> A (hop2)
    k_hop_agg<<<cBN / 4, 256, 0, stream>>>(hwB, ssrcB, sdstB, row_ptr, esrc, gcsr, h_bf, khsum,
                                           agg_bf, 1, W_hop + 2 * 4096, a_src + 2 * cH,
                                           a_dst + 2 * cH, hwA, ssrcA, sdstA, 1);
    // hop2: read A, no tail
    k_hop_agg<<<cBN / 4, 256, 0, stream>>>(hwA, ssrcA, sdstA, row_ptr, esrc, gcsr, h_bf, khsum,
                                           agg_bf, 2, nullptr, nullptr, nullptr, nullptr,
                                           nullptr, nullptr, 0);
    // dense chain + cell + next-step hop0 matvec tail -> A
    k_mega<<<NBLK, 256, 0, stream>>>(x, t, h_nm, h_bf, khsum, agg_bf, row_ptr, Wtg, Wenc, Wlt,
                                     Whop, a_src, a_dst, hwA, ssrcA, sdstA, b_tau, b_g, b_enc,
                                     gamma, beta, c_enc, c_dec, W_dec, b_dec, (float*)d_out);
  }
}

// Round 15
// 488.385 us; speedup vs baseline: 1.1289x; 1.1289x over previous
//
#include <hip/hip_runtime.h>
#include <hip/hip_bf16.h>
#include <math.h>

// SeaLiceGLKAN — fp32 in/out. R13(533us) structure: standalone MFMA hop matvecs,
// softmax edge aggregate (4 edges/iter, quarter-wave, dwordx2 gathers),
// MFMA mega-kernel (dense chain + cell + next-step hop0 matvec tail).

constexpr int cB = 2, cT = 4, cN = 10000, cF = 16, cH = 64, cE = 160000, cK = 3;
constexpr int cBN = cB * cN;    // 20000
constexpr int cBNH = cBN * cH;  // 1,280,000
constexpr int NBLK = (cBN + 63) / 64;  // 313 nodegroups of 64

typedef const float* fp;
typedef short short8 __attribute__((ext_vector_type(8)));
typedef float f32x4 __attribute__((ext_vector_type(4)));
typedef unsigned short u16;

__device__ __forceinline__ float wsum(float v) {
#pragma unroll
  for (int o = 1; o < 64; o <<= 1) v += __shfl_xor(v, o, 64);
  return v;
}
__device__ __forceinline__ u16 f2b(float f) {  // fp32 -> bf16 bits (RNE)
  unsigned u = __float_as_uint(f);
  u += 0x7FFFu + ((u >> 16) & 1u);
  return (u16)(u >> 16);
}
__device__ __forceinline__ float b2f(u16 b) { return __uint_as_float(((unsigned)b) << 16); }

// ---------------- CSR build ----------------
__global__ void k_count(const int* dst, int* counts) {
  int e = blockIdx.x * 256 + threadIdx.x;
  if (e < cE) atomicAdd(&counts[dst[e]], 1);
}

__global__ void k_scan(const int* counts, int* row_ptr, int* cursor) {
  __shared__ int part[1024];
  int t = threadIdx.x;
  const int CH = (cN + 1023) / 1024;  // 10
  int s = 0;
  for (int i = 0; i < CH; i++) {
    int idx = t * CH + i;
    if (idx < cN) s += counts[idx];
  }
  part[t] = s;
  __syncthreads();
  for (int off = 1; off < 1024; off <<= 1) {
    int v = (t >= off) ? part[t - off] : 0;
    __syncthreads();
    part[t] += v;
    __syncthreads();
  }
  int excl = (t == 0) ? 0 : part[t - 1];
  for (int i = 0; i < CH; i++) {
    int idx = t * CH + i;
    if (idx < cN) {
      row_ptr[idx] = excl;
      cursor[idx] = excl;
      excl += counts[idx];
    }
  }
  if (t == 1023) row_ptr[cN] = part[1023];
}

__global__ void k_scatter(const int* src, const int* dst, fp ea, fp w1, fp b1, fp w2, fp b2,
                          int* cursor, int* esrc, float* gcsr) {
  int e = blockIdx.x * 256 + threadIdx.x;
  if (e >= cE) return;
  float a0 = ea[e * 4 + 0], a1 = ea[e * 4 + 1], a2 = ea[e * 4 + 2], a3 = ea[e * 4 + 3];
  float acc = b2[0];
#pragma unroll
  for (int j = 0; j < 16; j++) {
    float tv = b1[j] + a0 * w1[j] + a1 * w1[16 + j] + a2 * w1[32 + j] + a3 * w1[48 + j];
    acc += tanhf(tv) * w2[j];
  }
  float g = 1.f / (1.f + expf(-acc));
  int p = atomicAdd(&cursor[dst[e]], 1);
  esrc[p] = src[e];
  gcsr[p] = g;
}

// ---------------- setup: counts zero + h init + weight prepack ----------------
constexpr int cWTOT = 128 * 160 + 64 * 128 + 64 * 64 + 3 * 64 * 64;  // 45056
__global__ void k_setup(int* counts, float* h, u16* h_bf, fp h0, fp W_tau, fp W_g, fp W_enc,
                        fp W_lt, fp W_hop, u16* Wtg, u16* Wenc, u16* Wlt, u16* Whop) {
  int i = blockIdx.x * 256 + threadIdx.x;
  if (i < cN) counts[i] = 0;
  if (i < cBNH) {
    float v = h0[i & 63];
    h[i] = v;
    h_bf[i] = f2b(v);
  }
  if (i < 128 * 160) {
    int col = i / 160, k = i - col * 160;
    float v = 0.f;
    if (k < 133) v = (col < 64) ? W_tau[k * 64 + col] : W_g[k * 64 + (col - 64)];
    Wtg[i] = f2b(v);
  } else if (i < 128 * 160 + 64 * 128) {
    int i2 = i - 128 * 160;
    int col = i2 / 128, k = i2 - col * 128;
    Wenc[i2] = f2b(W_enc[k * 64 + col]);
  } else if (i < 128 * 160 + 64 * 128 + 64 * 64) {
    int i3 = i - 128 * 160 - 64 * 128;
    int col = i3 / 64, k = i3 - col * 64;
    Wlt[i3] = f2b(W_lt[k * 64 + col]);
  } else if (i < cWTOT) {
    int i4 = i - 128 * 160 - 64 * 128 - 64 * 64;
    int hop = i4 / 4096, rem = i4 - hop * 4096;
    int col = rem / 64, k = rem - col * 64;
    Whop[i4] = f2b(W_hop[hop * 4096 + k * 64 + col]);
  }
}

// ---------------- hop matvec: MFMA, bf16 in/out ----------------
__global__ __launch_bounds__(256) void k_hop_mat_m(const u16* vin_bf, const u16* Wh, fp avs,
                                                   fp avd, u16* hw_bf, float* ssrc,
                                                   float* sdst) {
  __shared__ u16 tin[64 * 72];
  __shared__ u16 thw[64 * 72];
  __shared__ float red1[4][64], red2[4][64];
  int tid = threadIdx.x, w = tid >> 6, lane = tid & 63;
  int quad = lane >> 4, l15 = lane & 15;
  int base = blockIdx.x * 64;
  {
    int tn = tid >> 2, cs = (tid & 3) * 16;
    int gn = base + tn;
    if (gn >= cBN) gn = cBN - 1;
    const short8* src = (const short8*)(vin_bf + (size_t)gn * 64 + cs);
    *(short8*)(tin + tn * 72 + cs) = src[0];
    *(short8*)(tin + tn * 72 + cs + 8) = src[1];
  }
  __syncthreads();
  f32x4 acc[4];
#pragma unroll
  for (int mt = 0; mt < 4; mt++) acc[mt] = (f32x4){0.f, 0.f, 0.f, 0.f};
#pragma unroll
  for (int ks = 0; ks < 2; ks++) {
    short8 bfr = *(const short8*)(Wh + (16 * w + l15) * 64 + ks * 32 + quad * 8);
#pragma unroll
    for (int mt = 0; mt < 4; mt++) {
      short8 afr = *(const short8*)(tin + (mt * 16 + l15) * 72 + ks * 32 + quad * 8);
      acc[mt] = __builtin_amdgcn_mfma_f32_16x16x32_bf16(afr, bfr, acc[mt], 0, 0, 0);
    }
  }
  int col = 16 * w + l15;
#pragma unroll
  for (int mt = 0; mt < 4; mt++) {
#pragma unroll
    for (int r = 0; r < 4; r++) {
      thw[(mt * 16 + quad * 4 + r) * 72 + col] = f2b(acc[mt][r]);
    }
  }
  __syncthreads();
  {
    float r1 = 0.f, r2 = 0.f;
#pragma unroll
    for (int c = 0; c < 16; c++) {
      float v = b2f(thw[lane * 72 + 16 * w + c]);
      r1 += v * avs[16 * w + c];
      r2 += v * avd[16 * w + c];
    }
    red1[w][lane] = r1;
    red2[w][lane] = r2;
  }
  __syncthreads();
  if (w == 0 && base + lane < cBN) {
    ssrc[base + lane] = red1[0][lane] + red1[1][lane] + red1[2][lane] + red1[3][lane];
    sdst[base + lane] = red2[0][lane] + red2[1][lane] + red2[2][lane] + red2[3][lane];
  }
  {
    int tn = tid >> 2, cs = (tid & 3) * 16;
    int gn = base + tn;
    if (gn < cBN) {
      short8* dst = (short8*)(hw_bf + (size_t)gn * 64 + cs);
      dst[0] = *(const short8*)(thw + tn * 72 + cs);
      dst[1] = *(const short8*)(thw + tn * 72 + cs + 8);
    }
  }
}

// ---------------- hop aggregate: 4 edges/iter, quarter-wave, dwordx2 gathers -----------
__global__ __launch_bounds__(256) void k_hop_agg(const u16* hw_bf, const float* ssrc,
                                                 const float* sdst, const int* row_ptr,
                                                 const int* esrc, const float* gcsr,
                                                 const u16* h_bf, u16* cur_bf, float* khsum,
                                                 u16* agg_bf, int hop) {
  int w = threadIdx.x >> 6, lane = threadIdx.x & 63;
  int q = lane >> 4, ql = lane & 15;
  int u = blockIdx.x * 4 + w;
  int b = u / cN, n = u - b * cN;
  int r0 = row_ptr[n], r1e = row_ptr[n + 1];
  const float* sb = ssrc + (size_t)b * cN;
  float sd = sdst[u];
  float den = 0.f;
  float num0 = 0.f, num1 = 0.f, num2 = 0.f, num3 = 0.f;
  float la0 = 0.f, la1 = 0.f, la2 = 0.f, la3 = 0.f;
  const u16* hwb = hw_bf + (size_t)b * cN * 64;
  const u16* hb = h_bf + (size_t)b * cN * 64;
  for (int e0 = r0; e0 < r1e; e0 += 64) {
    int e = e0 + lane;
    bool vld = e < r1e;
    int s = vld ? esrc[e] : 0;
    float g = (hop == 0 && vld) ? gcsr[e] : 0.f;
    float a = 0.f;
    if (vld) {
      float ev = sb[s] + sd;
      ev = ev > 0.f ? ev : 0.2f * ev;
      a = __expf(ev);  // |ev| small; softmax shift-invariant
    }
    den += a;
    int cnt = min(64, r1e - e0);
    for (int j = 0; j < cnt; j += 4) {
      // quarter q handles edge j+q (a=0 pads tails); lane covers cols ql*4..+3
      int sj = __shfl(s, j + q, 64);
      float aj = __shfl(a, j + q, 64);
      uint2 d = *(const uint2*)(hwb + (size_t)sj * 64 + ql * 4);
      num0 += aj * __uint_as_float(d.x << 16);
      num1 += aj * __uint_as_float(d.x & 0xffff0000u);
      num2 += aj * __uint_as_float(d.y << 16);
      num3 += aj * __uint_as_float(d.y & 0xffff0000u);
      if (hop == 0) {
        float gj = __shfl(g, j + q, 64);
        uint2 dh = *(const uint2*)(hb + (size_t)sj * 64 + ql * 4);
        la0 += gj * __uint_as_float(dh.x << 16);
        la1 += gj * __uint_as_float(dh.x & 0xffff0000u);
        la2 += gj * __uint_as_float(dh.y << 16);
        la3 += gj * __uint_as_float(dh.y & 0xffff0000u);
      }
    }
  }
  den = wsum(den);
  num0 += __shfl_xor(num0, 16); num0 += __shfl_xor(num0, 32);
  num1 += __shfl_xor(num1, 16); num1 += __shfl_xor(num1, 32);
  num2 += __shfl_xor(num2, 16); num2 += __shfl_xor(num2, 32);
  num3 += __shfl_xor(num3, 16); num3 += __shfl_xor(num3, 32);
  if (hop == 0) {
    la0 += __shfl_xor(la0, 16); la0 += __shfl_xor(la0, 32);
    la1 += __shfl_xor(la1, 16); la1 += __shfl_xor(la1, 32);
    la2 += __shfl_xor(la2, 16); la2 += __shfl_xor(la2, 32);
    la3 += __shfl_xor(la3, 16); la3 += __shfl_xor(la3, 32);
  }
  if (q == 0) {
    float inv = 1.f / (den + 1e-16f);
    float c0 = num0 * inv, c1 = num1 * inv, c2 = num2 * inv, c3 = num3 * inv;
    size_t ni = (size_t)u * 64 + ql * 4;
    if (hop < 2) {
      uint2 pk;
      pk.x = ((unsigned)f2b(c1) << 16) | (unsigned)f2b(c0);
      pk.y = ((unsigned)f2b(c3) << 16) | (unsigned)f2b(c2);
      *(uint2*)(cur_bf + ni) = pk;
    }
    float4* kp = (float4*)(khsum + ni);
    if (hop == 0) {
      float4 kv;
      kv.x = c0; kv.y = c1; kv.z = c2; kv.w = c3;
      *kp = kv;
      uint2 ga;
      ga.x = ((unsigned)f2b(la1) << 16) | (unsigned)f2b(la0);
      ga.y = ((unsigned)f2b(la3) << 16) | (unsigned)f2b(la2);
      *(uint2*)(agg_bf + ni) = ga;
    } else {
      float4 kv = *kp;
      kv.x += c0; kv.y += c1; kv.z += c2; kv.w += c3;
      *kp = kv;
    }
  }
}

// ---------------- MFMA mega-kernel: p-GEMM + tau/g GEMM + u GEMM + cell + next hop0 mat --
__global__ __launch_bounds__(256) void k_mega(fp x, int t, float* h_nm, u16* h_bf,
                                              const float* khsum, const u16* agg_bf,
                                              const int* row_ptr, const u16* Wtg,
                                              const u16* Wenc, const u16* Wlt, const u16* Whop0,
                                              fp avs0, fp avd0, u16* hw_bf, float* ssrc,
                                              float* sdst, fp b_tau, fp b_g, fp b_enc, fp gamma,
                                              fp beta, fp c_enc, fp cdec, fp W_dec, fp b_dec,
                                              float* out) {
  __shared__ __align__(16) char lds[59904];
  u16* tz = (u16*)lds;                  // [64][168] bf16
  u16* tphi = (u16*)(lds + 30720);      // [64][136] bf16
  float* tgu = (float*)lds;             // [64][197] fp32 overlay (after GEMMs)
  u16* tzh = (u16*)lds;                 // [64][72] bf16 (tail overlay)
  u16* thw2 = (u16*)(lds + 10240);      // [64][72] bf16 (tail overlay)
  float* sx = (float*)(lds + 50432);
  float* redm = (float*)(lds + 54784);  // [4][64]
  float* redv = redm + 256;             // [4][64]
  float* redp = redv + 256;             // [4][3][64]
  int tid = threadIdx.x;
  int w = tid >> 6, lane = tid & 63;
  int quad = lane >> 4, l15 = lane & 15;
  int base = blockIdx.x * 64;
  {
    int tn = tid >> 2, f4 = (tid & 3) * 4;
    int gn = base + tn;
    if (gn >= cBN) gn = cBN - 1;
    int gb = gn / cN, gnn = gn - gb * cN;
    float4 xv = *(const float4*)(x + (((size_t)gb * cT + t) * cN + gnn) * cF + f4);
    sx[tn * 17 + f4 + 0] = xv.x;
    sx[tn * 17 + f4 + 1] = xv.y;
    sx[tn * 17 + f4 + 2] = xv.z;
    sx[tn * 17 + f4 + 3] = xv.w;
    int f0 = (tid & 3) * 16;
    const short8* hs = (const short8*)(h_bf + (size_t)gn * 64 + f0);
    *(short8*)(tz + tn * 168 + f0) = hs[0];
    *(short8*)(tz + tn * 168 + f0 + 8) = hs[1];
  }
  for (int i = tid; i < 64 * 27; i += 256) {
    int nn2 = i / 27;
    tz[nn2 * 168 + 133 + (i - nn2 * 27)] = 0;
  }
  __syncthreads();
  for (int i = tid; i < 320; i += 256) {
    int j = i >> 6, n2 = i & 63;
    tz[n2 * 168 + 64 + j] = f2b(sx[n2 * 17 + 8 + j]);
  }
  {
    float ec0 = c_enc[0], ec7 = c_enc[7];
    float inv_e = 7.f / (ec7 - ec0);
    for (int i = tid; i < 64 * 128; i += 256) {
      int n2 = i >> 7, j = i & 127;
      int f = j >> 3, cb = j & 7;
      float d = (sx[n2 * 17 + f] - c_enc[cb]) * inv_e;
      tphi[n2 * 136 + j] = f2b(__expf(-d * d));
    }
  }
  __syncthreads();
  // G2: u = phi @ Wenc
  f32x4 accU[4];
#pragma unroll
  for (int mt = 0; mt < 4; mt++) accU[mt] = (f32x4){0.f, 0.f, 0.f, 0.f};
#pragma unroll
  for (int ks = 0; ks < 4; ks++) {
    short8 bfr = *(const short8*)(Wenc + (16 * w + l15) * 128 + ks * 32 + quad * 8);
#pragma unroll
    for (int mt = 0; mt < 4; mt++) {
      short8 afr = *(const short8*)(tphi + (mt * 16 + l15) * 136 + ks * 32 + quad * 8);
      accU[mt] = __builtin_amdgcn_mfma_f32_16x16x32_bf16(afr, bfr, accU[mt], 0, 0, 0);
    }
  }
  // G0: plt = agg @ Wlt -> p rows into tz
  {
    f32x4 accP[4];
#pragma unroll
    for (int mt = 0; mt < 4; mt++) accP[mt] = (f32x4){0.f, 0.f, 0.f, 0.f};
#pragma unroll
    for (int ks = 0; ks < 2; ks++) {
      short8 bfr = *(const short8*)(Wlt + (16 * w + l15) * 64 + ks * 32 + quad * 8);
#pragma unroll
      for (int mt = 0; mt < 4; mt++) {
        int gn = base + mt * 16 + l15;
        if (gn >= cBN) gn = cBN - 1;
        short8 afr = *(const short8*)(agg_bf + (size_t)gn * 64 + ks * 32 + quad * 8);
        accP[mt] = __builtin_amdgcn_mfma_f32_16x16x32_bf16(afr, bfr, accP[mt], 0, 0, 0);
      }
    }
    int colP = 16 * w + l15;
#pragma unroll
    for (int mt = 0; mt < 4; mt++) {
#pragma unroll
      for (int r = 0; r < 4; r++) {
        int nl = mt * 16 + quad * 4 + r;
        int gn = base + nl;
        int gnc = gn < cBN ? gn : cBN - 1;
        int bB = gnc / cN, nn = gnc - bB * cN;
        float deg = (float)(row_ptr[nn + 1] - row_ptr[nn]);
        float pv = khsum[(size_t)gnc * 64 + colP] * (1.f / 3.f) + accP[mt][r] / (deg + 1.f);
        tz[nl * 168 + 69 + colP] = f2b(pv);
      }
    }
  }
  __syncthreads();
  // G1: [tau|g] = z @ Wtg (K=160)
  f32x4 accT[8];
#pragma unroll
  for (int i = 0; i < 8; i++) accT[i] = (f32x4){0.f, 0.f, 0.f, 0.f};
#pragma unroll
  for (int ks = 0; ks < 5; ks++) {
    short8 b0 = *(const short8*)(Wtg + (32 * w + l15) * 160 + ks * 32 + quad * 8);
    short8 b1 = *(const short8*)(Wtg + (32 * w + 16 + l15) * 160 + ks * 32 + quad * 8);
#pragma unroll
    for (int mt = 0; mt < 4; mt++) {
      short8 afr = *(const short8*)(tz + (mt * 16 + l15) * 168 + ks * 32 + quad * 8);
      accT[mt * 2 + 0] =
          __builtin_amdgcn_mfma_f32_16x16x32_bf16(afr, b0, accT[mt * 2 + 0], 0, 0, 0);
      accT[mt * 2 + 1] =
          __builtin_amdgcn_mfma_f32_16x16x32_bf16(afr, b1, accT[mt * 2 + 1], 0, 0, 0);
    }
  }
  __syncthreads();  // tz dead; tgu overlay
#pragma unroll
  for (int mt = 0; mt < 4; mt++) {
#pragma unroll
    for (int ntl = 0; ntl < 2; ntl++) {
#pragma unroll
      for (int r = 0; r < 4; r++) {
        int nl = mt * 16 + quad * 4 + r;
        tgu[nl * 197 + 32 * w + ntl * 16 + l15] = accT[mt * 2 + ntl][r];
      }
    }
#pragma unroll
    for (int r = 0; r < 4; r++) {
      int nl = mt * 16 + quad * 4 + r;
      tgu[nl * 197 + 128 + 16 * w + l15] = accU[mt][r];
    }
  }
  __syncthreads();
  // epilogue: thread = node lane, col chunk c0
  int c0 = __builtin_amdgcn_readfirstlane(w * 16);
  int node = base + lane;
  int ngc = node < cBN ? node : cBN - 1;
  int bb = ngc / cN, nn = ngc - bb * cN;
  float hv[16];
  {
    const float4* hp = (const float4*)(h_nm + (size_t)ngc * 64 + c0);
#pragma unroll
    for (int q = 0; q < 4; q++) {
      float4 v = hp[q];
      hv[q * 4 + 0] = v.x; hv[q * 4 + 1] = v.y; hv[q * 4 + 2] = v.z; hv[q * 4 + 3] = v.w;
    }
  }
  float acc[16];
  float pm = 0.f;
#pragma unroll
  for (int c = 0; c < 16; c++) {
    float at = tgu[lane * 197 + c0 + c] + b_tau[c0 + c];
    float ag = tgu[lane * 197 + 64 + c0 + c] + b_g[c0 + c];
    float tau = 1.f + 9.f / (1.f + __expf(-at));
    float g = tanhf(ag);
    float v = hv[c] + 0.25f * (g - hv[c]) / tau;
    acc[c] = v;
    pm += v;
  }
  redm[w * 64 + lane] = pm;
  __syncthreads();
  float mu = (redm[lane] + redm[64 + lane] + redm[128 + lane] + redm[192 + lane]) * (1.f / 64.f);
  float pv = 0.f;
#pragma unroll
  for (int c = 0; c < 16; c++) {
    float d = acc[c] - mu;
    pv += d * d;
  }
  redv[w * 64 + lane] = pv;
  __syncthreads();
  float var = (redv[lane] + redv[64 + lane] + redv[128 + lane] + redv[192 + lane]) * (1.f / 64.f);
  float rstd = rsqrtf(var + 1e-5f);
#pragma unroll
  for (int c = 0; c < 16; c++) {
    acc[c] = (acc[c] - mu) * rstd * gamma[c0 + c] + beta[c0 + c] +
             tgu[lane * 197 + 128 + c0 + c] + b_enc[c0 + c];
  }
  if (node < cBN) {
    float4* hp = (float4*)(h_nm + (size_t)ngc * 64 + c0);
#pragma unroll
    for (int q = 0; q < 4; q++) {
      float4 v;
      v.x = acc[q * 4 + 0]; v.y = acc[q * 4 + 1]; v.z = acc[q * 4 + 2]; v.w = acc[q * 4 + 3];
      hp[q] = v;
    }
    unsigned* bp = (unsigned*)(h_bf + (size_t)ngc * 64 + c0);
#pragma unroll
    for (int q = 0; q < 8; q++) {
      unsigned lo = f2b(acc[q * 2 + 0]);
      unsigned hi = f2b(acc[q * 2 + 1]);
      bp[q] = (hi << 16) | lo;
    }
  }
  // decoder fastkan + softplus
  float dc0 = cdec[0], dc7 = cdec[7];
  float inv_d = 7.f / (dc7 - dc0);
  float p0 = 0.f, p1 = 0.f, p2 = 0.f;
#pragma unroll
  for (int c = 0; c < 16; c++) {
#pragma unroll
    for (int j = 0; j < 8; j++) {
      float dd = (acc[c] - cdec[j]) * inv_d;
      float ph = __expf(-dd * dd);
      int bx = ((c0 + c) * 8 + j) * 3;
      p0 += ph * W_dec[bx];
      p1 += ph * W_dec[bx + 1];
      p2 += ph * W_dec[bx + 2];
    }
  }
  redp[(w * 3 + 0) * 64 + lane] = p0;
  redp[(w * 3 + 1) * 64 + lane] = p1;
  redp[(w * 3 + 2) * 64 + lane] = p2;
  __syncthreads();  // also: all tgu reads complete -> tail overlay safe
  if (w == 0 && node < cBN) {
    float v0 = redp[0 * 64 + lane] + redp[3 * 64 + lane] + redp[6 * 64 + lane] +
               redp[9 * 64 + lane] + b_dec[0];
    float v1 = redp[1 * 64 + lane] + redp[4 * 64 + lane] + redp[7 * 64 + lane] +
               redp[10 * 64 + lane] + b_dec[1];
    float v2 = redp[2 * 64 + lane] + redp[5 * 64 + lane] + redp[8 * 64 + lane] +
               redp[11 * 64 + lane] + b_dec[2];
    size_t ob = (((size_t)bb * cT + t) * cN + nn) * 3;
    out[ob] = fmaxf(v0, 0.f) + log1pf(expf(-fabsf(v0)));
    out[ob + 1] = fmaxf(v1, 0.f) + log1pf(expf(-fabsf(v1)));
    out[ob + 2] = fmaxf(v2, 0.f) + log1pf(expf(-fabsf(v2)));
  }
  // ---- fused tail: next-step hop0 matvec (node-local: uses just-computed h) ----
#pragma unroll
  for (int c = 0; c < 16; c++) tzh[lane * 72 + c0 + c] = f2b(acc[c]);
  __syncthreads();
  f32x4 hacc[4];
#pragma unroll
  for (int mt = 0; mt < 4; mt++) hacc[mt] = (f32x4){0.f, 0.f, 0.f, 0.f};
#pragma unroll
  for (int ks = 0; ks < 2; ks++) {
    short8 bfr = *(const short8*)(Whop0 + (16 * w + l15) * 64 + ks * 32 + quad * 8);
#pragma unroll
    for (int mt = 0; mt < 4; mt++) {
      short8 afr = *(const short8*)(tzh + (mt * 16 + l15) * 72 + ks * 32 + quad * 8);
      hacc[mt] = __builtin_amdgcn_mfma_f32_16x16x32_bf16(afr, bfr, hacc[mt], 0, 0, 0);
    }
  }
  int colh = 16 * w + l15;
#pragma unroll
  for (int mt = 0; mt < 4; mt++) {
#pragma unroll
    for (int r = 0; r < 4; r++) {
      thw2[(mt * 16 + quad * 4 + r) * 72 + colh] = f2b(hacc[mt][r]);
    }
  }
  __syncthreads();
  {
    float r1 = 0.f, r2 = 0.f;
#pragma unroll
    for (int c = 0; c < 16; c++) {
      float v = b2f(thw2[lane * 72 + 16 * w + c]);
      r1 += v * avs0[16 * w + c];
      r2 += v * avd0[16 * w + c];
    }
    redm[w * 64 + lane] = r1;
    redv[w * 64 + lane] = r2;
  }
  __syncthreads();
  if (w == 0 && node < cBN) {
    ssrc[node] = redm[lane] + redm[64 + lane] + redm[128 + lane] + redm[192 + lane];
    sdst[node] = redv[lane] + redv[64 + lane] + redv[128 + lane] + redv[192 + lane];
  }
  {
    int tn = tid >> 2, cs = (tid & 3) * 16;
    int gn = base + tn;
    if (gn < cBN) {
      short8* dst = (short8*)(hw_bf + (size_t)gn * 64 + cs);
      dst[0] = *(const short8*)(thw2 + tn * 72 + cs);
      dst[1] = *(const short8*)(thw2 + tn * 72 + cs + 8);
    }
  }
}

extern "C" void kernel_launch(void* const* d_in, const int* in_sizes, int n_in, void* d_out,
                              int out_size, void* d_ws, size_t ws_size, hipStream_t stream) {
  fp x = (fp)d_in[0];
  fp edge_attr = (fp)d_in[1];
  fp c_enc = (fp)d_in[2];
  fp W_enc = (fp)d_in[3];
  fp b_enc = (fp)d_in[4];
  fp W_hop = (fp)d_in[5];
  fp a_src = (fp)d_in[6];
  fp a_dst = (fp)d_in[7];
  fp w_lt1 = (fp)d_in[8];
  fp b_lt1 = (fp)d_in[9];
  fp w_lt2 = (fp)d_in[10];
  fp b_lt2 = (fp)d_in[11];
  fp W_lt = (fp)d_in[12];
  fp W_tau = (fp)d_in[13];
  fp b_tau = (fp)d_in[14];
  fp W_g = (fp)d_in[15];
  fp b_g = (fp)d_in[16];
  fp gamma = (fp)d_in[17];
  fp beta = (fp)d_in[18];
  fp c_dec = (fp)d_in[19];
  fp W_dec = (fp)d_in[20];
  fp b_dec = (fp)d_in[21];
  fp h0 = (fp)d_in[22];
  const int* eidx = (const int*)d_in[23];
  const int* esrc_in = eidx;
  const int* edst_in = eidx + cE;

  float* fws = (float*)d_ws;
  float* h_nm = fws;   fws += cBNH;
  float* khsum = fws;  fws += cBNH;
  float* ssrc = fws;   fws += cBN;
  float* sdst = fws;   fws += cBN;
  float* gcsr = fws;   fws += cE;
  u16* h_bf = (u16*)fws;   fws += cBNH / 2;
  u16* hw_bf = (u16*)fws;  fws += cBNH / 2;
  u16* cur_bf = (u16*)fws; fws += cBNH / 2;
  u16* agg_bf = (u16*)fws; fws += cBNH / 2;
  u16* Wtg = (u16*)fws;   fws += (128 * 160) / 2;
  u16* Wenc = (u16*)fws;  fws += (64 * 128) / 2;
  u16* Wlt = (u16*)fws;   fws += (64 * 64) / 2;
  u16* Whop = (u16*)fws;  fws += (3 * 64 * 64) / 2;
  int* iws = (int*)fws;
  int* esrc = iws;    iws += cE;
  int* row_ptr = iws; iws += cN + 1;
  int* cursor = iws;  iws += cN;
  int* counts = iws;  iws += cN;

  k_setup<<<(cBNH + 255) / 256, 256, 0, stream>>>(counts, h_nm, h_bf, h0, W_tau, W_g, W_enc,
                                                  W_lt, W_hop, Wtg, Wenc, Wlt, Whop);
  k_count<<<(cE + 255) / 256, 256, 0, stream>>>(edst_in, counts);
  k_scan<<<1, 1024, 0, stream>>>(counts, row_ptr, cursor);
  k_scatter<<<(cE + 255) / 256, 256, 0, stream>>>(esrc_in, edst_in, edge_attr, w_lt1, b_lt1,
                                                  w_lt2, b_lt2, cursor, esrc, gcsr);
  // initial hop0 matvec for t=0 (later steps get it fused into k_mega's tail)
  k_hop_mat_m<<<NBLK, 256, 0, stream>>>(h_bf, Whop, a_src, a_dst, hw_bf, ssrc, sdst);

  for (int t = 0; t < cT; t++) {
    for (int k = 0; k < cK; k++) {
      if (k > 0) {
        k_hop_mat_m<<<NBLK, 256, 0, stream>>>(cur_bf, Whop + k * 4096, a_src + k * cH,
                                              a_dst + k * cH, hw_bf, ssrc, sdst);
      }
      k_hop_agg<<<cBN / 4, 256, 0, stream>>>(hw_bf, ssrc, sdst, row_ptr, esrc, gcsr, h_bf,
                                             cur_bf, khsum, agg_bf, k);
    }
    k_mega<<<NBLK, 256, 0, stream>>>(x, t, h_nm, h_bf, khsum, agg_bf, row_ptr, Wtg, Wenc, Wlt,
                                     Whop, a_src, a_dst, hw_bf, ssrc, sdst, b_tau, b_g, b_enc,
                                     gamma, beta, c_enc, c_dec, W_dec, b_dec, (float*)d_out);
  }
}

// Round 16
// 475.186 us; speedup vs baseline: 1.1603x; 1.0278x over previous
//
#include <hip/hip_runtime.h>
#include <hip/hip_bf16.h>
#include <math.h>

// SeaLiceGLKAN — fp32 in/out. R15 structure + RBF geometric recurrence
// (2 exps per 8-basis bundle instead of 8) and exp-based tanh.

constexpr int cB = 2, cT = 4, cN = 10000, cF = 16, cH = 64, cE = 160000, cK = 3;
constexpr int cBN = cB * cN;    // 20000
constexpr int cBNH = cBN * cH;  // 1,280,000
constexpr int NBLK = (cBN + 63) / 64;  // 313 nodegroups of 64

typedef const float* fp;
typedef short short8 __attribute__((ext_vector_type(8)));
typedef float f32x4 __attribute__((ext_vector_type(4)));
typedef unsigned short u16;

constexpr float cEXPM2 = 0.13533528323661270f;  // exp(-2)

__device__ __forceinline__ float wsum(float v) {
#pragma unroll
  for (int o = 1; o < 64; o <<= 1) v += __shfl_xor(v, o, 64);
  return v;
}
__device__ __forceinline__ u16 f2b(float f) {  // fp32 -> bf16 bits (RNE)
  unsigned u = __float_as_uint(f);
  u += 0x7FFFu + ((u >> 16) & 1u);
  return (u16)(u >> 16);
}
__device__ __forceinline__ float b2f(u16 b) { return __uint_as_float(((unsigned)b) << 16); }
__device__ __forceinline__ float ftanh(float x) {
  float e = __expf(2.f * x);
  return (e - 1.f) / (e + 1.f);
}

// ---------------- CSR build ----------------
__global__ void k_count(const int* dst, int* counts) {
  int e = blockIdx.x * 256 + threadIdx.x;
  if (e < cE) atomicAdd(&counts[dst[e]], 1);
}

__global__ void k_scan(const int* counts, int* row_ptr, int* cursor) {
  __shared__ int part[1024];
  int t = threadIdx.x;
  const int CH = (cN + 1023) / 1024;  // 10
  int s = 0;
  for (int i = 0; i < CH; i++) {
    int idx = t * CH + i;
    if (idx < cN) s += counts[idx];
  }
  part[t] = s;
  __syncthreads();
  for (int off = 1; off < 1024; off <<= 1) {
    int v = (t >= off) ? part[t - off] : 0;
    __syncthreads();
    part[t] += v;
    __syncthreads();
  }
  int excl = (t == 0) ? 0 : part[t - 1];
  for (int i = 0; i < CH; i++) {
    int idx = t * CH + i;
    if (idx < cN) {
      row_ptr[idx] = excl;
      cursor[idx] = excl;
      excl += counts[idx];
    }
  }
  if (t == 1023) row_ptr[cN] = part[1023];
}

__global__ void k_scatter(const int* src, const int* dst, fp ea, fp w1, fp b1, fp w2, fp b2,
                          int* cursor, int* esrc, float* gcsr) {
  int e = blockIdx.x * 256 + threadIdx.x;
  if (e >= cE) return;
  float a0 = ea[e * 4 + 0], a1 = ea[e * 4 + 1], a2 = ea[e * 4 + 2], a3 = ea[e * 4 + 3];
  float acc = b2[0];
#pragma unroll
  for (int j = 0; j < 16; j++) {
    float tv = b1[j] + a0 * w1[j] + a1 * w1[16 + j] + a2 * w1[32 + j] + a3 * w1[48 + j];
    acc += ftanh(tv) * w2[j];
  }
  float g = 1.f / (1.f + __expf(-acc));
  int p = atomicAdd(&cursor[dst[e]], 1);
  esrc[p] = src[e];
  gcsr[p] = g;
}

// ---------------- setup: counts zero + h init + weight prepack ----------------
constexpr int cWTOT = 128 * 160 + 64 * 128 + 64 * 64 + 3 * 64 * 64;  // 45056
__global__ void k_setup(int* counts, float* h, u16* h_bf, fp h0, fp W_tau, fp W_g, fp W_enc,
                        fp W_lt, fp W_hop, u16* Wtg, u16* Wenc, u16* Wlt, u16* Whop) {
  int i = blockIdx.x * 256 + threadIdx.x;
  if (i < cN) counts[i] = 0;
  if (i < cBNH) {
    float v = h0[i & 63];
    h[i] = v;
    h_bf[i] = f2b(v);
  }
  if (i < 128 * 160) {
    int col = i / 160, k = i - col * 160;
    float v = 0.f;
    if (k < 133) v = (col < 64) ? W_tau[k * 64 + col] : W_g[k * 64 + (col - 64)];
    Wtg[i] = f2b(v);
  } else if (i < 128 * 160 + 64 * 128) {
    int i2 = i - 128 * 160;
    int col = i2 / 128, k = i2 - col * 128;
    Wenc[i2] = f2b(W_enc[k * 64 + col]);
  } else if (i < 128 * 160 + 64 * 128 + 64 * 64) {
    int i3 = i - 128 * 160 - 64 * 128;
    int col = i3 / 64, k = i3 - col * 64;
    Wlt[i3] = f2b(W_lt[k * 64 + col]);
  } else if (i < cWTOT) {
    int i4 = i - 128 * 160 - 64 * 128 - 64 * 64;
    int hop = i4 / 4096, rem = i4 - hop * 4096;
    int col = rem / 64, k = rem - col * 64;
    Whop[i4] = f2b(W_hop[hop * 4096 + k * 64 + col]);
  }
}

// ---------------- hop matvec: MFMA, bf16 in/out ----------------
__global__ __launch_bounds__(256) void k_hop_mat_m(const u16* vin_bf, const u16* Wh, fp avs,
                                                   fp avd, u16* hw_bf, float* ssrc,
                                                   float* sdst) {
  __shared__ u16 tin[64 * 72];
  __shared__ u16 thw[64 * 72];
  __shared__ float red1[4][64], red2[4][64];
  int tid = threadIdx.x, w = tid >> 6, lane = tid & 63;
  int quad = lane >> 4, l15 = lane & 15;
  int base = blockIdx.x * 64;
  {
    int tn = tid >> 2, cs = (tid & 3) * 16;
    int gn = base + tn;
    if (gn >= cBN) gn = cBN - 1;
    const short8* src = (const short8*)(vin_bf + (size_t)gn * 64 + cs);
    *(short8*)(tin + tn * 72 + cs) = src[0];
    *(short8*)(tin + tn * 72 + cs + 8) = src[1];
  }
  __syncthreads();
  f32x4 acc[4];
#pragma unroll
  for (int mt = 0; mt < 4; mt++) acc[mt] = (f32x4){0.f, 0.f, 0.f, 0.f};
#pragma unroll
  for (int ks = 0; ks < 2; ks++) {
    short8 bfr = *(const short8*)(Wh + (16 * w + l15) * 64 + ks * 32 + quad * 8);
#pragma unroll
    for (int mt = 0; mt < 4; mt++) {
      short8 afr = *(const short8*)(tin + (mt * 16 + l15) * 72 + ks * 32 + quad * 8);
      acc[mt] = __builtin_amdgcn_mfma_f32_16x16x32_bf16(afr, bfr, acc[mt], 0, 0, 0);
    }
  }
  int col = 16 * w + l15;
#pragma unroll
  for (int mt = 0; mt < 4; mt++) {
#pragma unroll
    for (int r = 0; r < 4; r++) {
      thw[(mt * 16 + quad * 4 + r) * 72 + col] = f2b(acc[mt][r]);
    }
  }
  __syncthreads();
  {
    float r1 = 0.f, r2 = 0.f;
#pragma unroll
    for (int c = 0; c < 16; c++) {
      float v = b2f(thw[lane * 72 + 16 * w + c]);
      r1 += v * avs[16 * w + c];
      r2 += v * avd[16 * w + c];
    }
    red1[w][lane] = r1;
    red2[w][lane] = r2;
  }
  __syncthreads();
  if (w == 0 && base + lane < cBN) {
    ssrc[base + lane] = red1[0][lane] + red1[1][lane] + red1[2][lane] + red1[3][lane];
    sdst[base + lane] = red2[0][lane] + red2[1][lane] + red2[2][lane] + red2[3][lane];
  }
  {
    int tn = tid >> 2, cs = (tid & 3) * 16;
    int gn = base + tn;
    if (gn < cBN) {
      short8* dst = (short8*)(hw_bf + (size_t)gn * 64 + cs);
      dst[0] = *(const short8*)(thw + tn * 72 + cs);
      dst[1] = *(const short8*)(thw + tn * 72 + cs + 8);
    }
  }
}

// ---------------- hop aggregate: 4 edges/iter, quarter-wave, dwordx2 gathers -----------
__global__ __launch_bounds__(256) void k_hop_agg(const u16* hw_bf, const float* ssrc,
                                                 const float* sdst, const int* row_ptr,
                                                 const int* esrc, const float* gcsr,
                                                 const u16* h_bf, u16* cur_bf, float* khsum,
                                                 u16* agg_bf, int hop) {
  int w = threadIdx.x >> 6, lane = threadIdx.x & 63;
  int q = lane >> 4, ql = lane & 15;
  int u = blockIdx.x * 4 + w;
  int b = u / cN, n = u - b * cN;
  int r0 = row_ptr[n], r1e = row_ptr[n + 1];
  const float* sb = ssrc + (size_t)b * cN;
  float sd = sdst[u];
  float den = 0.f;
  float num0 = 0.f, num1 = 0.f, num2 = 0.f, num3 = 0.f;
  float la0 = 0.f, la1 = 0.f, la2 = 0.f, la3 = 0.f;
  const u16* hwb = hw_bf + (size_t)b * cN * 64;
  const u16* hb = h_bf + (size_t)b * cN * 64;
  for (int e0 = r0; e0 < r1e; e0 += 64) {
    int e = e0 + lane;
    bool vld = e < r1e;
    int s = vld ? esrc[e] : 0;
    float g = (hop == 0 && vld) ? gcsr[e] : 0.f;
    float a = 0.f;
    if (vld) {
      float ev = sb[s] + sd;
      ev = ev > 0.f ? ev : 0.2f * ev;
      a = __expf(ev);  // |ev| small; softmax shift-invariant
    }
    den += a;
    int cnt = min(64, r1e - e0);
    for (int j = 0; j < cnt; j += 4) {
      // quarter q handles edge j+q (a=0 pads tails); lane covers cols ql*4..+3
      int sj = __shfl(s, j + q, 64);
      float aj = __shfl(a, j + q, 64);
      uint2 d = *(const uint2*)(hwb + (size_t)sj * 64 + ql * 4);
      num0 += aj * __uint_as_float(d.x << 16);
      num1 += aj * __uint_as_float(d.x & 0xffff0000u);
      num2 += aj * __uint_as_float(d.y << 16);
      num3 += aj * __uint_as_float(d.y & 0xffff0000u);
      if (hop == 0) {
        float gj = __shfl(g, j + q, 64);
        uint2 dh = *(const uint2*)(hb + (size_t)sj * 64 + ql * 4);
        la0 += gj * __uint_as_float(dh.x << 16);
        la1 += gj * __uint_as_float(dh.x & 0xffff0000u);
        la2 += gj * __uint_as_float(dh.y << 16);
        la3 += gj * __uint_as_float(dh.y & 0xffff0000u);
      }
    }
  }
  den = wsum(den);
  num0 += __shfl_xor(num0, 16); num0 += __shfl_xor(num0, 32);
  num1 += __shfl_xor(num1, 16); num1 += __shfl_xor(num1, 32);
  num2 += __shfl_xor(num2, 16); num2 += __shfl_xor(num2, 32);
  num3 += __shfl_xor(num3, 16); num3 += __shfl_xor(num3, 32);
  if (hop == 0) {
    la0 += __shfl_xor(la0, 16); la0 += __shfl_xor(la0, 32);
    la1 += __shfl_xor(la1, 16); la1 += __shfl_xor(la1, 32);
    la2 += __shfl_xor(la2, 16); la2 += __shfl_xor(la2, 32);
    la3 += __shfl_xor(la3, 16); la3 += __shfl_xor(la3, 32);
  }
  if (q == 0) {
    float inv = 1.f / (den + 1e-16f);
    float c0 = num0 * inv, c1 = num1 * inv, c2 = num2 * inv, c3 = num3 * inv;
    size_t ni = (size_t)u * 64 + ql * 4;
    if (hop < 2) {
      uint2 pk;
      pk.x = ((unsigned)f2b(c1) << 16) | (unsigned)f2b(c0);
      pk.y = ((unsigned)f2b(c3) << 16) | (unsigned)f2b(c2);
      *(uint2*)(cur_bf + ni) = pk;
    }
    float4* kp = (float4*)(khsum + ni);
    if (hop == 0) {
      float4 kv;
      kv.x = c0; kv.y = c1; kv.z = c2; kv.w = c3;
      *kp = kv;
      uint2 ga;
      ga.x = ((unsigned)f2b(la1) << 16) | (unsigned)f2b(la0);
      ga.y = ((unsigned)f2b(la3) << 16) | (unsigned)f2b(la2);
      *(uint2*)(agg_bf + ni) = ga;
    } else {
      float4 kv = *kp;
      kv.x += c0; kv.y += c1; kv.z += c2; kv.w += c3;
      *kp = kv;
    }
  }
}

// ---------------- MFMA mega-kernel: p-GEMM + tau/g GEMM + u GEMM + cell + next hop0 mat --
__global__ __launch_bounds__(256) void k_mega(fp x, int t, float* h_nm, u16* h_bf,
                                              const float* khsum, const u16* agg_bf,
                                              const int* row_ptr, const u16* Wtg,
                                              const u16* Wenc, const u16* Wlt, const u16* Whop0,
                                              fp avs0, fp avd0, u16* hw_bf, float* ssrc,
                                              float* sdst, fp b_tau, fp b_g, fp b_enc, fp gamma,
                                              fp beta, fp c_enc, fp cdec, fp W_dec, fp b_dec,
                                              float* out) {
  __shared__ __align__(16) char lds[59904];
  u16* tz = (u16*)lds;                  // [64][168] bf16
  u16* tphi = (u16*)(lds + 30720);      // [64][136] bf16
  float* tgu = (float*)lds;             // [64][197] fp32 overlay (after GEMMs)
  u16* tzh = (u16*)lds;                 // [64][72] bf16 (tail overlay)
  u16* thw2 = (u16*)(lds + 10240);      // [64][72] bf16 (tail overlay)
  float* sx = (float*)(lds + 50432);
  float* redm = (float*)(lds + 54784);  // [4][64]
  float* redv = redm + 256;             // [4][64]
  float* redp = redv + 256;             // [4][3][64]
  int tid = threadIdx.x;
  int w = tid >> 6, lane = tid & 63;
  int quad = lane >> 4, l15 = lane & 15;
  int base = blockIdx.x * 64;
  {
    int tn = tid >> 2, f4 = (tid & 3) * 4;
    int gn = base + tn;
    if (gn >= cBN) gn = cBN - 1;
    int gb = gn / cN, gnn = gn - gb * cN;
    float4 xv = *(const float4*)(x + (((size_t)gb * cT + t) * cN + gnn) * cF + f4);
    sx[tn * 17 + f4 + 0] = xv.x;
    sx[tn * 17 + f4 + 1] = xv.y;
    sx[tn * 17 + f4 + 2] = xv.z;
    sx[tn * 17 + f4 + 3] = xv.w;
    int f0 = (tid & 3) * 16;
    const short8* hs = (const short8*)(h_bf + (size_t)gn * 64 + f0);
    *(short8*)(tz + tn * 168 + f0) = hs[0];
    *(short8*)(tz + tn * 168 + f0 + 8) = hs[1];
  }
  for (int i = tid; i < 64 * 27; i += 256) {
    int nn2 = i / 27;
    tz[nn2 * 168 + 133 + (i - nn2 * 27)] = 0;
  }
  __syncthreads();
  for (int i = tid; i < 320; i += 256) {
    int j = i >> 6, n2 = i & 63;
    tz[n2 * 168 + 64 + j] = f2b(sx[n2 * 17 + 8 + j]);
  }
  // phi via RBF recurrence: per (node,f) bundle, 2 exps for 8 bases
  {
    float ec0 = c_enc[0], ec7 = c_enc[7];
    float inv_e = 7.f / (ec7 - ec0);
    for (int i = tid; i < 64 * 16; i += 256) {
      int n2 = i >> 4, f = i & 15;
      float d0 = (sx[n2 * 17 + f] - ec0) * inv_e;
      float phi = __expf(-d0 * d0);
      float r = __expf(2.f * d0 - 1.f);
      u16* dst = tphi + n2 * 136 + f * 8;
#pragma unroll
      for (int cb = 0; cb < 8; cb++) {
        dst[cb] = f2b(phi);
        phi *= r;
        r *= cEXPM2;
      }
    }
  }
  __syncthreads();
  // G2: u = phi @ Wenc
  f32x4 accU[4];
#pragma unroll
  for (int mt = 0; mt < 4; mt++) accU[mt] = (f32x4){0.f, 0.f, 0.f, 0.f};
#pragma unroll
  for (int ks = 0; ks < 4; ks++) {
    short8 bfr = *(const short8*)(Wenc + (16 * w + l15) * 128 + ks * 32 + quad * 8);
#pragma unroll
    for (int mt = 0; mt < 4; mt++) {
      short8 afr = *(const short8*)(tphi + (mt * 16 + l15) * 136 + ks * 32 + quad * 8);
      accU[mt] = __builtin_amdgcn_mfma_f32_16x16x32_bf16(afr, bfr, accU[mt], 0, 0, 0);
    }
  }
  // G0: plt = agg @ Wlt -> p rows into tz
  {
    f32x4 accP[4];
#pragma unroll
    for (int mt = 0; mt < 4; mt++) accP[mt] = (f32x4){0.f, 0.f, 0.f, 0.f};
#pragma unroll
    for (int ks = 0; ks < 2; ks++) {
      short8 bfr = *(const short8*)(Wlt + (16 * w + l15) * 64 + ks * 32 + quad * 8);
#pragma unroll
      for (int mt = 0; mt < 4; mt++) {
        int gn = base + mt * 16 + l15;
        if (gn >= cBN) gn = cBN - 1;
        short8 afr = *(const short8*)(agg_bf + (size_t)gn * 64 + ks * 32 + quad * 8);
        accP[mt] = __builtin_amdgcn_mfma_f32_16x16x32_bf16(afr, bfr, accP[mt], 0, 0, 0);
      }
    }
    int colP = 16 * w + l15;
#pragma unroll
    for (int mt = 0; mt < 4; mt++) {
#pragma unroll
      for (int r = 0; r < 4; r++) {
        int nl = mt * 16 + quad * 4 + r;
        int gn = base + nl;
        int gnc = gn < cBN ? gn : cBN - 1;
        int bB = gnc / cN, nn = gnc - bB * cN;
        float deg = (float)(row_ptr[nn + 1] - row_ptr[nn]);
        float pv = khsum[(size_t)gnc * 64 + colP] * (1.f / 3.f) + accP[mt][r] / (deg + 1.f);
        tz[nl * 168 + 69 + colP] = f2b(pv);
      }
    }
  }
  __syncthreads();
  // G1: [tau|g] = z @ Wtg (K=160)
  f32x4 accT[8];
#pragma unroll
  for (int i = 0; i < 8; i++) accT[i] = (f32x4){0.f, 0.f, 0.f, 0.f};
#pragma unroll
  for (int ks = 0; ks < 5; ks++) {
    short8 b0 = *(const short8*)(Wtg + (32 * w + l15) * 160 + ks * 32 + quad * 8);
    short8 b1 = *(const short8*)(Wtg + (32 * w + 16 + l15) * 160 + ks * 32 + quad * 8);
#pragma unroll
    for (int mt = 0; mt < 4; mt++) {
      short8 afr = *(const short8*)(tz + (mt * 16 + l15) * 168 + ks * 32 + quad * 8);
      accT[mt * 2 + 0] =
          __builtin_amdgcn_mfma_f32_16x16x32_bf16(afr, b0, accT[mt * 2 + 0], 0, 0, 0);
      accT[mt * 2 + 1] =
          __builtin_amdgcn_mfma_f32_16x16x32_bf16(afr, b1, accT[mt * 2 + 1], 0, 0, 0);
    }
  }
  __syncthreads();  // tz dead; tgu overlay
#pragma unroll
  for (int mt = 0; mt < 4; mt++) {
#pragma unroll
    for (int ntl = 0; ntl < 2; ntl++) {
#pragma unroll
      for (int r = 0; r < 4; r++) {
        int nl = mt * 16 + quad * 4 + r;
        tgu[nl * 197 + 32 * w + ntl * 16 + l15] = accT[mt * 2 + ntl][r];
      }
    }
#pragma unroll
    for (int r = 0; r < 4; r++) {
      int nl = mt * 16 + quad * 4 + r;
      tgu[nl * 197 + 128 + 16 * w + l15] = accU[mt][r];
    }
  }
  __syncthreads();
  // epilogue: thread = node lane, col chunk c0
  int c0 = __builtin_amdgcn_readfirstlane(w * 16);
  int node = base + lane;
  int ngc = node < cBN ? node : cBN - 1;
  int bb = ngc / cN, nn = ngc - bb * cN;
  float hv[16];
  {
    const float4* hp = (const float4*)(h_nm + (size_t)ngc * 64 + c0);
#pragma unroll
    for (int q = 0; q < 4; q++) {
      float4 v = hp[q];
      hv[q * 4 + 0] = v.x; hv[q * 4 + 1] = v.y; hv[q * 4 + 2] = v.z; hv[q * 4 + 3] = v.w;
    }
  }
  float acc[16];
  float pm = 0.f;
#pragma unroll
  for (int c = 0; c < 16; c++) {
    float at = tgu[lane * 197 + c0 + c] + b_tau[c0 + c];
    float ag = tgu[lane * 197 + 64 + c0 + c] + b_g[c0 + c];
    float tau = 1.f + 9.f / (1.f + __expf(-at));
    float g = ftanh(ag);
    float v = hv[c] + 0.25f * (g - hv[c]) / tau;
    acc[c] = v;
    pm += v;
  }
  redm[w * 64 + lane] = pm;
  __syncthreads();
  float mu = (redm[lane] + redm[64 + lane] + redm[128 + lane] + redm[192 + lane]) * (1.f / 64.f);
  float pv = 0.f;
#pragma unroll
  for (int c = 0; c < 16; c++) {
    float d = acc[c] - mu;
    pv += d * d;
  }
  redv[w * 64 + lane] = pv;
  __syncthreads();
  float var = (redv[lane] + redv[64 + lane] + redv[128 + lane] + redv[192 + lane]) * (1.f / 64.f);
  float rstd = rsqrtf(var + 1e-5f);
#pragma unroll
  for (int c = 0; c < 16; c++) {
    acc[c] = (acc[c] - mu) * rstd * gamma[c0 + c] + beta[c0 + c] +
             tgu[lane * 197 + 128 + c0 + c] + b_enc[c0 + c];
  }
  if (node < cBN) {
    float4* hp = (float4*)(h_nm + (size_t)ngc * 64 + c0);
#pragma unroll
    for (int q = 0; q < 4; q++) {
      float4 v;
      v.x = acc[q * 4 + 0]; v.y = acc[q * 4 + 1]; v.z = acc[q * 4 + 2]; v.w = acc[q * 4 + 3];
      hp[q] = v;
    }
    unsigned* bp = (unsigned*)(h_bf + (size_t)ngc * 64 + c0);
#pragma unroll
    for (int q = 0; q < 8; q++) {
      unsigned lo = f2b(acc[q * 2 + 0]);
      unsigned hi = f2b(acc[q * 2 + 1]);
      bp[q] = (hi << 16) | lo;
    }
  }
  // decoder fastkan (RBF recurrence: 2 exps per col) + softplus
  float dc0 = cdec[0], dc7 = cdec[7];
  float inv_d = 7.f / (dc7 - dc0);
  float p0 = 0.f, p1 = 0.f, p2 = 0.f;
#pragma unroll
  for (int c = 0; c < 16; c++) {
    float d0 = (acc[c] - dc0) * inv_d;
    float ph = __expf(-d0 * d0);
    float r = __expf(2.f * d0 - 1.f);
    const float* Wd = W_dec + (c0 + c) * 24;
#pragma unroll
    for (int j = 0; j < 8; j++) {
      p0 += ph * Wd[j * 3];
      p1 += ph * Wd[j * 3 + 1];
      p2 += ph * Wd[j * 3 + 2];
      ph *= r;
      r *= cEXPM2;
    }
  }
  redp[(w * 3 + 0) * 64 + lane] = p0;
  redp[(w * 3 + 1) * 64 + lane] = p1;
  redp[(w * 3 + 2) * 64 + lane] = p2;
  __syncthreads();  // also: all tgu reads complete -> tail overlay safe
  if (w == 0 && node < cBN) {
    float v0 = redp[0 * 64 + lane] + redp[3 * 64 + lane] + redp[6 * 64 + lane] +
               redp[9 * 64 + lane] + b_dec[0];
    float v1 = redp[1 * 64 + lane] + redp[4 * 64 + lane] + redp[7 * 64 + lane] +
               redp[10 * 64 + lane] + b_dec[1];
    float v2 = redp[2 * 64 + lane] + redp[5 * 64 + lane] + redp[8 * 64 + lane] +
               redp[11 * 64 + lane] + b_dec[2];
    size_t ob = (((size_t)bb * cT + t) * cN + nn) * 3;
    out[ob] = fmaxf(v0, 0.f) + log1pf(__expf(-fabsf(v0)));
    out[ob + 1] = fmaxf(v1, 0.f) + log1pf(__expf(-fabsf(v1)));
    out[ob + 2] = fmaxf(v2, 0.f) + log1pf(__expf(-fabsf(v2)));
  }
  // ---- fused tail: next-step hop0 matvec (node-local: uses just-computed h) ----
#pragma unroll
  for (int c = 0; c < 16; c++) tzh[lane * 72 + c0 + c] = f2b(acc[c]);
  __syncthreads();
  f32x4 hacc[4];
#pragma unroll
  for (int mt = 0; mt < 4; mt++) hacc[mt] = (f32x4){0.f, 0.f, 0.f, 0.f};
#pragma unroll
  for (int ks = 0; ks < 2; ks++) {
    short8 bfr = *(const short8*)(Whop0 + (16 * w + l15) * 64 + ks * 32 + quad * 8);
#pragma unroll
    for (int mt = 0; mt < 4; mt++) {
      short8 afr = *(const short8*)(tzh + (mt * 16 + l15) * 72 + ks * 32 + quad * 8);
      hacc[mt] = __builtin_amdgcn_mfma_f32_16x16x32_bf16(afr, bfr, hacc[mt], 0, 0, 0);
    }
  }
  int colh = 16 * w + l15;
#pragma unroll
  for (int mt = 0; mt < 4; mt++) {
#pragma unroll
    for (int r = 0; r < 4; r++) {
      thw2[(mt * 16 + quad * 4 + r) * 72 + colh] = f2b(hacc[mt][r]);
    }
  }
  __syncthreads();
  {
    float r1 = 0.f, r2 = 0.f;
#pragma unroll
    for (int c = 0; c < 16; c++) {
      float v = b2f(thw2[lane * 72 + 16 * w + c]);
      r1 += v * avs0[16 * w + c];
      r2 += v * avd0[16 * w + c];
    }
    redm[w * 64 + lane] = r1;
    redv[w * 64 + lane] = r2;
  }
  __syncthreads();
  if (w == 0 && node < cBN) {
    ssrc[node] = redm[lane] + redm[64 + lane] + redm[128 + lane] + redm[192 + lane];
    sdst[node] = redv[lane] + redv[64 + lane] + redv[128 + lane] + redv[192 + lane];
  }
  {
    int tn = tid >> 2, cs = (tid & 3) * 16;
    int gn = base + tn;
    if (gn < cBN) {
      short8* dst = (short8*)(hw_bf + (size_t)gn * 64 + cs);
      dst[0] = *(const short8*)(thw2 + tn * 72 + cs);
      dst[1] = *(const short8*)(thw2 + tn * 72 + cs + 8);
    }
  }
}

extern "C" void kernel_launch(void* const* d_in, const int* in_sizes, int n_in, void* d_out,
                              int out_size, void* d_ws, size_t ws_size, hipStream_t stream) {
  fp x = (fp)d_in[0];
  fp edge_attr = (fp)d_in[1];
  fp c_enc = (fp)d_in[2];
  fp W_enc = (fp)d_in[3];
  fp b_enc = (fp)d_in[4];
  fp W_hop = (fp)d_in[5];
  fp a_src = (fp)d_in[6];
  fp a_dst = (fp)d_in[7];
  fp w_lt1 = (fp)d_in[8];
  fp b_lt1 = (fp)d_in[9];
  fp w_lt2 = (fp)d_in[10];
  fp b_lt2 = (fp)d_in[11];
  fp W_lt = (fp)d_in[12];
  fp W_tau = (fp)d_in[13];
  fp b_tau = (fp)d_in[14];
  fp W_g = (fp)d_in[15];
  fp b_g = (fp)d_in[16];
  fp gamma = (fp)d_in[17];
  fp beta = (fp)d_in[18];
  fp c_dec = (fp)d_in[19];
  fp W_dec = (fp)d_in[20];
  fp b_dec = (fp)d_in[21];
  fp h0 = (fp)d_in[22];
  const int* eidx = (const int*)d_in[23];
  const int* esrc_in = eidx;
  const int* edst_in = eidx + cE;

  float* fws = (float*)d_ws;
  float* h_nm = fws;   fws += cBNH;
  float* khsum = fws;  fws += cBNH;
  float* ssrc = fws;   fws += cBN;
  float* sdst = fws;   fws += cBN;
  float* gcsr = fws;   fws += cE;
  u16* h_bf = (u16*)fws;   fws += cBNH / 2;
  u16* hw_bf = (u16*)fws;  fws += cBNH / 2;
  u16* cur_bf = (u16*)fws; fws += cBNH / 2;
  u16* agg_bf = (u16*)fws; fws += cBNH / 2;
  u16* Wtg = (u16*)fws;   fws += (128 * 160) / 2;
  u16* Wenc = (u16*)fws;  fws += (64 * 128) / 2;
  u16* Wlt = (u16*)fws;   fws += (64 * 64) / 2;
  u16* Whop = (u16*)fws;  fws += (3 * 64 * 64) / 2;
  int* iws = (int*)fws;
  int* esrc = iws;    iws += cE;
  int* row_ptr = iws; iws += cN + 1;
  int* cursor = iws;  iws += cN;
  int* counts = iws;  iws += cN;

  k_setup<<<(cBNH + 255) / 256, 256, 0, stream>>>(counts, h_nm, h_bf, h0, W_tau, W_g, W_enc,
                                                  W_lt, W_hop, Wtg, Wenc, Wlt, Whop);
  k_count<<<(cE + 255) / 256, 256, 0, stream>>>(edst_in, counts);
  k_scan<<<1, 1024, 0, stream>>>(counts, row_ptr, cursor);
  k_scatter<<<(cE + 255) / 256, 256, 0, stream>>>(esrc_in, edst_in, edge_attr, w_lt1, b_lt1,
                                                  w_lt2, b_lt2, cursor, esrc, gcsr);
  // initial hop0 matvec for t=0 (later steps get it fused into k_mega's tail)
  k_hop_mat_m<<<NBLK, 256, 0, stream>>>(h_bf, Whop, a_src, a_dst, hw_bf, ssrc, sdst);

  for (int t = 0; t < cT; t++) {
    for (int k = 0; k < cK; k++) {
      if (k > 0) {
        k_hop_mat_m<<<NBLK, 256, 0, stream>>>(cur_bf, Whop + k * 4096, a_src + k * cH,
                                              a_dst + k * cH, hw_bf, ssrc, sdst);
      }
      k_hop_agg<<<cBN / 4, 256, 0, stream>>>(hw_bf, ssrc, sdst, row_ptr, esrc, gcsr, h_bf,
                                             cur_bf, khsum, agg_bf, k);
    }
    k_mega<<<NBLK, 256, 0, stream>>>(x, t, h_nm, h_bf, khsum, agg_bf, row_ptr, Wtg, Wenc, Wlt,
                                     Whop, a_src, a_dst, hw_bf, ssrc, sdst, b_tau, b_g, b_enc,
                                     gamma, beta, c_enc, c_dec, W_dec, b_dec, (float*)d_out);
  }
}